// Round 1
// baseline (13440.063 us; speedup 1.0000x reference)
//
#include <hip/hip_runtime.h>
#include <stdint.h>

#define E_DIM 2048
#define H_DIM 2048
#define B_DIM 512
#define T_DIM 256
#define G4H   8192  // 4*H

typedef unsigned short u16;
typedef __attribute__((ext_vector_type(8))) short bf16x8;
typedef __attribute__((ext_vector_type(4))) float f32x4;

__device__ inline u16 f2b(float f) {
  union { float f; uint32_t i; } v; v.f = f;
  uint32_t u = v.i;
  return (u16)((u + 0x7FFFu + ((u >> 16) & 1u)) >> 16);  // RNE
}
__device__ inline float b2f(u16 u) {
  union { uint32_t i; float f; } v; v.i = ((uint32_t)u) << 16; return v.f;
}

__global__ __launch_bounds__(256) void convert_bf16(const float* __restrict__ s,
                                                    u16* __restrict__ d, int n4) {
  int i = blockIdx.x * 256 + threadIdx.x;
  if (i < n4) {
    float4 f = ((const float4*)s)[i];
    ushort4 o;
    o.x = f2b(f.x); o.y = f2b(f.y); o.z = f2b(f.z); o.w = f2b(f.w);
    ((ushort4*)d)[i] = o;
  }
}

// C[M,N] = A[M,K] @ B[N,K]^T ; A,B bf16 row-major (K contiguous), C f32.
// Tile: BM=64, BN=128, BK=32. 4 waves, each owns 32x64 (2x4 of 16x16 frags).
#define BM 64
#define BN 128
#define BK 32
__global__ __launch_bounds__(256) void gemm_bt(const u16* __restrict__ A,
                                               const u16* __restrict__ Bm,
                                               float* __restrict__ C,
                                               int M, int N, int K) {
  __shared__ u16 sA[BM * BK];  // 4 KB
  __shared__ u16 sB[BN * BK];  // 8 KB
  const int t = threadIdx.x;
  const int bm0 = blockIdx.y * BM, bn0 = blockIdx.x * BN;
  const int wave = t >> 6, lane = t & 63;
  const int wm = (wave >> 1) * 32, wn = (wave & 1) * 64;
  const int r16 = lane & 15, quad = lane >> 4;

  f32x4 acc[2][4];
  const f32x4 z = {0.f, 0.f, 0.f, 0.f};
  for (int i = 0; i < 2; ++i)
    for (int j = 0; j < 4; ++j) acc[i][j] = z;

  // staging indices: one 16B chunk = 8 bf16; A tile: 256 chunks, B tile: 512.
  const int arow = t >> 2, acg = t & 3;  // A: thread -> chunk t

  for (int k0 = 0; k0 < K; k0 += BK) {
    __syncthreads();
    *(uint4*)&sA[arow * BK + acg * 8] =
        *(const uint4*)&A[(size_t)(bm0 + arow) * K + k0 + acg * 8];
    for (int i = 0; i < 2; ++i) {
      int c = t + 256 * i;
      int row = c >> 2, cg = c & 3;
      *(uint4*)&sB[row * BK + cg * 8] =
          *(const uint4*)&Bm[(size_t)(bn0 + row) * K + k0 + cg * 8];
    }
    __syncthreads();
    bf16x8 af[2], bfr[4];
    for (int mt = 0; mt < 2; ++mt)
      af[mt] = *(const bf16x8*)&sA[(wm + mt * 16 + r16) * BK + quad * 8];
    for (int nt = 0; nt < 4; ++nt)
      bfr[nt] = *(const bf16x8*)&sB[(wn + nt * 16 + r16) * BK + quad * 8];
    for (int mt = 0; mt < 2; ++mt)
      for (int nt = 0; nt < 4; ++nt)
        acc[mt][nt] = __builtin_amdgcn_mfma_f32_16x16x32_bf16(af[mt], bfr[nt],
                                                              acc[mt][nt], 0, 0, 0);
  }
  // D: col(n) = lane&15, row(m) = quad*4 + reg  [m89/m91-verified]
  for (int mt = 0; mt < 2; ++mt)
    for (int nt = 0; nt < 4; ++nt) {
      int row = bm0 + wm + mt * 16 + quad * 4;
      int col = bn0 + wn + nt * 16 + r16;
      for (int r = 0; r < 4; ++r)
        C[(size_t)(row + r) * N + col] = acc[mt][nt][r];
    }
}

__global__ __launch_bounds__(256) void init_state(const float* __restrict__ h0pre,
                                                  const float* __restrict__ b_embed,
                                                  u16* __restrict__ h,
                                                  float* __restrict__ c,
                                                  float* __restrict__ x) {
  int idx = blockIdx.x * 256 + threadIdx.x;  // B*H
  int j = idx & (H_DIM - 1);
  float v = h0pre[idx] + b_embed[j];
  h[idx] = f2b(v);
  c[idx] = 0.f;
  if (idx < B_DIM * 2) x[idx] = 0.f;
}

__global__ __launch_bounds__(256) void lstm_update(const float* __restrict__ Gt,
                                                   const float* __restrict__ W_ih,
                                                   const float* __restrict__ b_ih,
                                                   const float* __restrict__ b_hh,
                                                   const float* __restrict__ x,
                                                   float* __restrict__ c,
                                                   u16* __restrict__ h) {
  int idx = blockIdx.x * 256 + threadIdx.x;  // B*H
  int b = idx >> 11, j = idx & (H_DIM - 1);
  float x0 = x[b * 2 + 0], x1 = x[b * 2 + 1];
  const float* g = Gt + (size_t)b * G4H;
  int ri = j, rf = H_DIM + j, rg = 2 * H_DIM + j, ro = 3 * H_DIM + j;
  float gi = g[ri] + b_ih[ri] + b_hh[ri] + x0 * W_ih[ri * 2] + x1 * W_ih[ri * 2 + 1];
  float gf = g[rf] + b_ih[rf] + b_hh[rf] + x0 * W_ih[rf * 2] + x1 * W_ih[rf * 2 + 1];
  float gg = g[rg] + b_ih[rg] + b_hh[rg] + x0 * W_ih[rg * 2] + x1 * W_ih[rg * 2 + 1];
  float go = g[ro] + b_ih[ro] + b_hh[ro] + x0 * W_ih[ro * 2] + x1 * W_ih[ro * 2 + 1];
  float si = 1.f / (1.f + __expf(-gi));
  float sf = 1.f / (1.f + __expf(-gf));
  float so = 1.f / (1.f + __expf(-go));
  float cn = sf * c[idx] + si * tanhf(gg);
  c[idx] = cn;
  h[idx] = f2b(so * tanhf(cn));
}

__global__ __launch_bounds__(256) void out_head(const u16* __restrict__ h,
                                                const float* __restrict__ W_out,
                                                const float* __restrict__ b_out,
                                                const float* __restrict__ W_stop,
                                                const float* __restrict__ b_stop,
                                                float* __restrict__ coords,
                                                float* __restrict__ stops,
                                                float* __restrict__ x, int t) {
  int b = blockIdx.x;
  int tid = threadIdx.x;
  float s0 = 0.f, s1 = 0.f, s2 = 0.f;
  for (int j = tid; j < H_DIM; j += 256) {
    float hv = b2f(h[b * H_DIM + j]);
    s0 += hv * W_out[j];
    s1 += hv * W_out[H_DIM + j];
    s2 += hv * W_stop[j];
  }
  for (int off = 32; off > 0; off >>= 1) {
    s0 += __shfl_down(s0, off);
    s1 += __shfl_down(s1, off);
    s2 += __shfl_down(s2, off);
  }
  __shared__ float red[4][3];
  int wave = tid >> 6, lane = tid & 63;
  if (lane == 0) { red[wave][0] = s0; red[wave][1] = s1; red[wave][2] = s2; }
  __syncthreads();
  if (tid == 0) {
    float c0 = red[0][0] + red[1][0] + red[2][0] + red[3][0] + b_out[0];
    float c1 = red[0][1] + red[1][1] + red[2][1] + red[3][1] + b_out[1];
    float sv = red[0][2] + red[1][2] + red[2][2] + red[3][2] + b_stop[0];
    float st = 1.f / (1.f + __expf(-sv));
    coords[((size_t)b * T_DIM + t) * 2 + 0] = c0;
    coords[((size_t)b * T_DIM + t) * 2 + 1] = c1;
    stops[(size_t)b * T_DIM + t] = st;
    x[b * 2 + 0] = c0;
    x[b * 2 + 1] = c1;
  }
}

extern "C" void kernel_launch(void* const* d_in, const int* in_sizes, int n_in,
                              void* d_out, int out_size, void* d_ws, size_t ws_size,
                              hipStream_t stream) {
  const float* embedding = (const float*)d_in[0];
  const float* W_embed   = (const float*)d_in[2];
  const float* b_embed   = (const float*)d_in[3];
  const float* W_ih      = (const float*)d_in[4];
  const float* b_ih      = (const float*)d_in[5];
  const float* W_hh      = (const float*)d_in[6];
  const float* b_hh      = (const float*)d_in[7];
  const float* W_out     = (const float*)d_in[8];
  const float* b_out     = (const float*)d_in[9];
  const float* W_stop    = (const float*)d_in[10];
  const float* b_stop    = (const float*)d_in[11];

  float* coords = (float*)d_out;                       // (B, T, 2)
  float* stops  = (float*)d_out + (size_t)B_DIM * T_DIM * 2;  // (B, T, 1)

  char* ws = (char*)d_ws;
  u16* W_hh_b  = (u16*)ws;  ws += (size_t)G4H * H_DIM * 2;    // 32 MB
  u16* W_emb_b = (u16*)ws;  ws += (size_t)H_DIM * E_DIM * 2;  // 8 MB
  u16* emb_b   = (u16*)ws;  ws += (size_t)B_DIM * E_DIM * 2;  // 2 MB
  float* gates = (float*)ws; ws += (size_t)B_DIM * G4H * 4;   // 16 MB (also h0 scratch)
  float* cbuf  = (float*)ws; ws += (size_t)B_DIM * H_DIM * 4; // 4 MB
  u16* hbuf    = (u16*)ws;  ws += (size_t)B_DIM * H_DIM * 2;  // 2 MB
  float* xbuf  = (float*)ws; ws += (size_t)B_DIM * 2 * 4;

  // 1) fp32 -> bf16 conversions (inputs are restored pristine every call)
  convert_bf16<<<(B_DIM * E_DIM / 4 + 255) / 256, 256, 0, stream>>>(embedding, emb_b, B_DIM * E_DIM / 4);
  convert_bf16<<<(H_DIM * E_DIM / 4 + 255) / 256, 256, 0, stream>>>(W_embed, W_emb_b, H_DIM * E_DIM / 4);
  convert_bf16<<<(G4H * H_DIM / 4 + 255) / 256, 256, 0, stream>>>(W_hh, W_hh_b, G4H * H_DIM / 4);

  // 2) h0 = emb @ W_embed^T  (h0 scratch lives in `gates`)
  gemm_bt<<<dim3(H_DIM / BN, B_DIM / BM), 256, 0, stream>>>(emb_b, W_emb_b, gates,
                                                            B_DIM, H_DIM, E_DIM);
  init_state<<<(B_DIM * H_DIM) / 256, 256, 0, stream>>>(gates, b_embed, hbuf, cbuf, xbuf);

  // 3) 256 sequential LSTM steps
  for (int t = 0; t < T_DIM; ++t) {
    gemm_bt<<<dim3(G4H / BN, B_DIM / BM), 256, 0, stream>>>(hbuf, W_hh_b, gates,
                                                            B_DIM, G4H, H_DIM);
    lstm_update<<<(B_DIM * H_DIM) / 256, 256, 0, stream>>>(gates, W_ih, b_ih, b_hh,
                                                           xbuf, cbuf, hbuf);
    out_head<<<B_DIM, 256, 0, stream>>>(hbuf, W_out, b_out, W_stop, b_stop,
                                        coords, stops, xbuf, t);
  }
}

// Round 2
// 10636.990 us; speedup vs baseline: 1.2635x; 1.2635x over previous
//
#include <hip/hip_runtime.h>
#include <stdint.h>

#define E_DIM 2048
#define H_DIM 2048
#define B_DIM 512
#define T_DIM 256
#define G4H   8192  // 4*H

typedef unsigned short u16;
typedef __attribute__((ext_vector_type(8))) short bf16x8;
typedef __attribute__((ext_vector_type(4))) float f32x4;

__device__ inline u16 f2b(float f) {
  union { float f; uint32_t i; } v; v.f = f;
  uint32_t u = v.i;
  return (u16)((u + 0x7FFFu + ((u >> 16) & 1u)) >> 16);  // RNE
}
__device__ inline float b2f(u16 u) {
  union { uint32_t i; float f; } v; v.i = ((uint32_t)u) << 16; return v.f;
}

// async global->LDS, 16B per lane. lptr MUST be wave-uniform (HW adds lane*16).
__device__ inline void async16(const void* g, void* l) {
  __builtin_amdgcn_global_load_lds(
      (const __attribute__((address_space(1))) uint32_t*)g,
      (__attribute__((address_space(3))) uint32_t*)l, 16, 0, 0);
}

__global__ __launch_bounds__(256) void convert_bf16(const float* __restrict__ s,
                                                    u16* __restrict__ d, int n4) {
  int i = blockIdx.x * 256 + threadIdx.x;
  if (i < n4) {
    float4 f = ((const float4*)s)[i];
    ushort4 o;
    o.x = f2b(f.x); o.y = f2b(f.y); o.z = f2b(f.z); o.w = f2b(f.w);
    ((ushort4*)d)[i] = o;
  }
}

// W_hh (4H x H) -> bf16, rows reordered to gate-interleaved: n' = j*4+g <- row g*H+j
__global__ __launch_bounds__(256) void reorder_whh(const float* __restrict__ s,
                                                   u16* __restrict__ d) {
  int i = blockIdx.x * 256 + threadIdx.x;     // float4-granule index, n4 = 4H*H/4
  int np = i >> 9;                            // H/4 = 512 granules per row
  int kg = i & 511;
  int src_row = (np & 3) * H_DIM + (np >> 2);
  float4 f = ((const float4*)s)[(size_t)src_row * 512 + kg];
  ushort4 o;
  o.x = f2b(f.x); o.y = f2b(f.y); o.z = f2b(f.z); o.w = f2b(f.w);
  ((ushort4*)d)[i] = o;
}

// epi[n'] = {b_ih+b_hh, W_ih[:,0], W_ih[:,1], 0} at interleaved row n'
__global__ __launch_bounds__(256) void build_epi(const float* __restrict__ b_ih,
                                                 const float* __restrict__ b_hh,
                                                 const float* __restrict__ W_ih,
                                                 float* __restrict__ epi) {
  int np = blockIdx.x * 256 + threadIdx.x;    // 0..8191
  int src = (np & 3) * H_DIM + (np >> 2);
  float4 e;
  e.x = b_ih[src] + b_hh[src];
  e.y = W_ih[src * 2];
  e.z = W_ih[src * 2 + 1];
  e.w = 0.f;
  ((float4*)epi)[np] = e;
}

// ---- plain GEMM (h0 path only, runs once) — round-1 verified code ----
#define BM 64
#define BN 128
#define BK 32
__global__ __launch_bounds__(256) void gemm_bt(const u16* __restrict__ A,
                                               const u16* __restrict__ Bm,
                                               float* __restrict__ C,
                                               int M, int N, int K) {
  __shared__ u16 sA[BM * BK];
  __shared__ u16 sB[BN * BK];
  const int t = threadIdx.x;
  const int bm0 = blockIdx.y * BM, bn0 = blockIdx.x * BN;
  const int wave = t >> 6, lane = t & 63;
  const int wm = (wave >> 1) * 32, wn = (wave & 1) * 64;
  const int r16 = lane & 15, quad = lane >> 4;

  f32x4 acc[2][4];
  const f32x4 z = {0.f, 0.f, 0.f, 0.f};
  for (int i = 0; i < 2; ++i)
    for (int j = 0; j < 4; ++j) acc[i][j] = z;

  const int arow = t >> 2, acg = t & 3;

  for (int k0 = 0; k0 < K; k0 += BK) {
    __syncthreads();
    *(uint4*)&sA[arow * BK + acg * 8] =
        *(const uint4*)&A[(size_t)(bm0 + arow) * K + k0 + acg * 8];
    for (int i = 0; i < 2; ++i) {
      int c = t + 256 * i;
      int row = c >> 2, cg = c & 3;
      *(uint4*)&sB[row * BK + cg * 8] =
          *(const uint4*)&Bm[(size_t)(bn0 + row) * K + k0 + cg * 8];
    }
    __syncthreads();
    bf16x8 af[2], bfr[4];
    for (int mt = 0; mt < 2; ++mt)
      af[mt] = *(const bf16x8*)&sA[(wm + mt * 16 + r16) * BK + quad * 8];
    for (int nt = 0; nt < 4; ++nt)
      bfr[nt] = *(const bf16x8*)&sB[(wn + nt * 16 + r16) * BK + quad * 8];
    for (int mt = 0; mt < 2; ++mt)
      for (int nt = 0; nt < 4; ++nt)
        acc[mt][nt] = __builtin_amdgcn_mfma_f32_16x16x32_bf16(af[mt], bfr[nt],
                                                              acc[mt][nt], 0, 0, 0);
  }
  for (int mt = 0; mt < 2; ++mt)
    for (int nt = 0; nt < 4; ++nt) {
      int row = bm0 + wm + mt * 16 + quad * 4;
      int col = bn0 + wn + nt * 16 + r16;
      for (int r = 0; r < 4; ++r)
        C[(size_t)(row + r) * N + col] = acc[mt][nt][r];
    }
}

// ---- fused step GEMM + LSTM pointwise epilogue ----
// A = h_in (B x H) bf16, Bm = W_hh_r (4H x H) bf16 gate-interleaved.
// Output: c (RMW, f32), h_out (bf16). h double-buffered by caller (blocks still
// read h_in as A while epilogue writes h_out).
__global__ __launch_bounds__(256) void gemm_lstm(const u16* __restrict__ A,
                                                 const u16* __restrict__ Bm,
                                                 const float* __restrict__ epi,
                                                 const float* __restrict__ x,
                                                 float* __restrict__ c,
                                                 u16* __restrict__ h_out) {
  __shared__ char smem[64 * 132 * 4];          // 33792 B, aliased
  u16* sA = (u16*)smem;                        // 4 KB (64 x 32)
  u16* sB = (u16*)(smem + 4096);               // 8 KB (128 x 32)
  float* gt = (float*)smem;                    // 64 x 132 f32 epilogue tile

  const int t = threadIdx.x;
  const int bn0 = blockIdx.x * BN, bm0 = blockIdx.y * BM;
  const int wv = t >> 6, ln = t & 63;
  const int wm = (wv >> 1) * 32, wn = (wv & 1) * 64;
  const int r16 = ln & 15, quad = ln >> 4;
  const int K = H_DIM;

  f32x4 acc[2][4];
  const f32x4 z = {0.f, 0.f, 0.f, 0.f};
  for (int i = 0; i < 2; ++i)
    for (int j = 0; j < 4; ++j) acc[i][j] = z;

  // staging geometry (16B chunks): A tile 256 chunks (1/thread), B tile 512 (2/thread)
  const int ca = wv * 64 + ln;                 // A chunk id
  const u16* gA = A + (size_t)(bm0 + (ca >> 2)) * K + (ca & 3) * 8;
  char* lA = smem + wv * 1024;                 // wave-uniform LDS dest

  const int cb0 = wv * 128 + ln;               // B chunk, instr 0
  const int cb1 = wv * 128 + 64 + ln;          // B chunk, instr 1
  const u16* gB0 = Bm + (size_t)(bn0 + (cb0 >> 2)) * K + (cb0 & 3) * 8;
  const u16* gB1 = Bm + (size_t)(bn0 + (cb1 >> 2)) * K + (cb1 & 3) * 8;
  char* lB0 = smem + 4096 + wv * 2048;         // wave-uniform
  char* lB1 = smem + 4096 + wv * 2048 + 1024;  // wave-uniform

  for (int k0 = 0; k0 < K; k0 += BK) {
    __syncthreads();                           // prev iter's frag reads done
    async16(gA + k0, lA);
    async16(gB0 + k0, lB0);
    async16(gB1 + k0, lB1);
    __syncthreads();                           // drains vmcnt, makes LDS visible
    bf16x8 af[2], bfr[4];
    for (int mt = 0; mt < 2; ++mt)
      af[mt] = *(const bf16x8*)&sA[(wm + mt * 16 + r16) * BK + quad * 8];
    for (int nt = 0; nt < 4; ++nt)
      bfr[nt] = *(const bf16x8*)&sB[(wn + nt * 16 + r16) * BK + quad * 8];
    for (int mt = 0; mt < 2; ++mt)
      for (int nt = 0; nt < 4; ++nt)
        acc[mt][nt] = __builtin_amdgcn_mfma_f32_16x16x32_bf16(af[mt], bfr[nt],
                                                              acc[mt][nt], 0, 0, 0);
  }

  // stage gate tile to LDS (stride 132 floats: 2-way bank aliasing only)
  __syncthreads();
  for (int mt = 0; mt < 2; ++mt)
    for (int nt = 0; nt < 4; ++nt) {
      int row = wm + mt * 16 + quad * 4;
      int col = wn + nt * 16 + r16;
      for (int r = 0; r < 4; ++r)
        gt[(row + r) * 132 + col] = acc[mt][nt][r];
    }
  __syncthreads();

  // LSTM pointwise: thread owns j_local = t&31, batch rows (t>>5)*8 .. +7
  const int jl = t & 31, bb = t >> 5;
  float4 e0 = ((const float4*)epi)[bn0 + jl * 4 + 0];
  float4 e1 = ((const float4*)epi)[bn0 + jl * 4 + 1];
  float4 e2 = ((const float4*)epi)[bn0 + jl * 4 + 2];
  float4 e3 = ((const float4*)epi)[bn0 + jl * 4 + 3];
  const int jg = (bn0 >> 2) + jl;
  for (int r = 0; r < 8; ++r) {
    int row = bb * 8 + r;
    int bg = bm0 + row;
    float x0 = x[bg * 2], x1 = x[bg * 2 + 1];
    float4 g4 = *(const float4*)&gt[row * 132 + jl * 4];
    float gi = g4.x + e0.x + x0 * e0.y + x1 * e0.z;
    float gf = g4.y + e1.x + x0 * e1.y + x1 * e1.z;
    float gg = g4.z + e2.x + x0 * e2.y + x1 * e2.z;
    float go = g4.w + e3.x + x0 * e3.y + x1 * e3.z;
    float si = 1.f / (1.f + __expf(-gi));
    float sf = 1.f / (1.f + __expf(-gf));
    float so = 1.f / (1.f + __expf(-go));
    size_t ci = (size_t)bg * H_DIM + jg;
    float cn = sf * c[ci] + si * tanhf(gg);
    c[ci] = cn;
    h_out[ci] = f2b(so * tanhf(cn));
  }
}

__global__ __launch_bounds__(256) void init_state(const float* __restrict__ h0pre,
                                                  const float* __restrict__ b_embed,
                                                  u16* __restrict__ h,
                                                  float* __restrict__ c,
                                                  float* __restrict__ x) {
  int idx = blockIdx.x * 256 + threadIdx.x;  // B*H
  int j = idx & (H_DIM - 1);
  float v = h0pre[idx] + b_embed[j];
  h[idx] = f2b(v);
  c[idx] = 0.f;
  if (idx < B_DIM * 2) x[idx] = 0.f;
}

__global__ __launch_bounds__(256) void out_head(const u16* __restrict__ h,
                                                const float* __restrict__ W_out,
                                                const float* __restrict__ b_out,
                                                const float* __restrict__ W_stop,
                                                const float* __restrict__ b_stop,
                                                float* __restrict__ coords,
                                                float* __restrict__ stops,
                                                float* __restrict__ x, int t) {
  int b = blockIdx.x;
  int tid = threadIdx.x;
  float s0 = 0.f, s1 = 0.f, s2 = 0.f;
  for (int j = tid; j < H_DIM; j += 256) {
    float hv = b2f(h[b * H_DIM + j]);
    s0 += hv * W_out[j];
    s1 += hv * W_out[H_DIM + j];
    s2 += hv * W_stop[j];
  }
  for (int off = 32; off > 0; off >>= 1) {
    s0 += __shfl_down(s0, off);
    s1 += __shfl_down(s1, off);
    s2 += __shfl_down(s2, off);
  }
  __shared__ float red[4][3];
  int wave = tid >> 6, lane = tid & 63;
  if (lane == 0) { red[wave][0] = s0; red[wave][1] = s1; red[wave][2] = s2; }
  __syncthreads();
  if (tid == 0) {
    float c0 = red[0][0] + red[1][0] + red[2][0] + red[3][0] + b_out[0];
    float c1 = red[0][1] + red[1][1] + red[2][1] + red[3][1] + b_out[1];
    float sv = red[0][2] + red[1][2] + red[2][2] + red[3][2] + b_stop[0];
    float st = 1.f / (1.f + __expf(-sv));
    coords[((size_t)b * T_DIM + t) * 2 + 0] = c0;
    coords[((size_t)b * T_DIM + t) * 2 + 1] = c1;
    stops[(size_t)b * T_DIM + t] = st;
    x[b * 2 + 0] = c0;
    x[b * 2 + 1] = c1;
  }
}

extern "C" void kernel_launch(void* const* d_in, const int* in_sizes, int n_in,
                              void* d_out, int out_size, void* d_ws, size_t ws_size,
                              hipStream_t stream) {
  const float* embedding = (const float*)d_in[0];
  const float* W_embed   = (const float*)d_in[2];
  const float* b_embed   = (const float*)d_in[3];
  const float* W_ih      = (const float*)d_in[4];
  const float* b_ih      = (const float*)d_in[5];
  const float* W_hh      = (const float*)d_in[6];
  const float* b_hh      = (const float*)d_in[7];
  const float* W_out     = (const float*)d_in[8];
  const float* b_out     = (const float*)d_in[9];
  const float* W_stop    = (const float*)d_in[10];
  const float* b_stop    = (const float*)d_in[11];

  float* coords = (float*)d_out;
  float* stops  = (float*)d_out + (size_t)B_DIM * T_DIM * 2;

  char* ws = (char*)d_ws;
  u16* W_hh_r  = (u16*)ws;   ws += (size_t)G4H * H_DIM * 2;    // 32 MB
  u16* W_emb_b = (u16*)ws;   ws += (size_t)H_DIM * E_DIM * 2;  // 8 MB
  u16* emb_b   = (u16*)ws;   ws += (size_t)B_DIM * E_DIM * 2;  // 2 MB
  float* h0pre = (float*)ws; ws += (size_t)B_DIM * H_DIM * 4;  // 4 MB
  float* epi   = (float*)ws; ws += (size_t)G4H * 4 * 4;        // 128 KB
  float* cbuf  = (float*)ws; ws += (size_t)B_DIM * H_DIM * 4;  // 4 MB
  u16* hbuf0   = (u16*)ws;   ws += (size_t)B_DIM * H_DIM * 2;  // 2 MB
  u16* hbuf1   = (u16*)ws;   ws += (size_t)B_DIM * H_DIM * 2;  // 2 MB
  float* xbuf  = (float*)ws; ws += (size_t)B_DIM * 2 * 4;

  // 1) conversions / reorders
  convert_bf16<<<(B_DIM * E_DIM / 4 + 255) / 256, 256, 0, stream>>>(embedding, emb_b, B_DIM * E_DIM / 4);
  convert_bf16<<<(H_DIM * E_DIM / 4 + 255) / 256, 256, 0, stream>>>(W_embed, W_emb_b, H_DIM * E_DIM / 4);
  reorder_whh<<<(G4H * H_DIM / 4) / 256, 256, 0, stream>>>(W_hh, W_hh_r);
  build_epi<<<G4H / 256, 256, 0, stream>>>(b_ih, b_hh, W_ih, epi);

  // 2) h0 = emb @ W_embed^T + b_embed
  gemm_bt<<<dim3(H_DIM / BN, B_DIM / BM), 256, 0, stream>>>(emb_b, W_emb_b, h0pre,
                                                            B_DIM, H_DIM, E_DIM);
  init_state<<<(B_DIM * H_DIM) / 256, 256, 0, stream>>>(h0pre, b_embed, hbuf0, cbuf, xbuf);

  // 3) 256 sequential fused steps (h ping-pong: epilogue writes while others read)
  for (int t = 0; t < T_DIM; ++t) {
    u16* h_in  = (t & 1) ? hbuf1 : hbuf0;
    u16* h_out = (t & 1) ? hbuf0 : hbuf1;
    gemm_lstm<<<dim3(G4H / BN, B_DIM / BM), 256, 0, stream>>>(h_in, W_hh_r, epi,
                                                              xbuf, cbuf, h_out);
    out_head<<<B_DIM, 256, 0, stream>>>(h_out, W_out, b_out, W_stop, b_stop,
                                        coords, stops, xbuf, t);
  }
}

// Round 3
// 9668.760 us; speedup vs baseline: 1.3901x; 1.1001x over previous
//
#include <hip/hip_runtime.h>
#include <stdint.h>

#define E_DIM 2048
#define H_DIM 2048
#define B_DIM 512
#define T_DIM 256
#define G4H   8192  // 4*H

typedef unsigned short u16;
typedef __attribute__((ext_vector_type(8))) short bf16x8;
typedef __attribute__((ext_vector_type(4))) float f32x4;

__device__ inline u16 f2b(float f) {
  union { float f; uint32_t i; } v; v.f = f;
  uint32_t u = v.i;
  return (u16)((u + 0x7FFFu + ((u >> 16) & 1u)) >> 16);  // RNE
}
__device__ inline float b2f(u16 u) {
  union { uint32_t i; float f; } v; v.i = ((uint32_t)u) << 16; return v.f;
}

__global__ __launch_bounds__(256) void convert_bf16(const float* __restrict__ s,
                                                    u16* __restrict__ d, int n4) {
  int i = blockIdx.x * 256 + threadIdx.x;
  if (i < n4) {
    float4 f = ((const float4*)s)[i];
    ushort4 o;
    o.x = f2b(f.x); o.y = f2b(f.y); o.z = f2b(f.z); o.w = f2b(f.w);
    ((ushort4*)d)[i] = o;
  }
}

// Build W in MFMA-B-fragment order. Chunk id = (n16*64 + k32)*64 + lane holds 8 bf16:
//   B[n' = n16*16 + (lane&15)][k = k32*32 + (lane>>4)*8 + j], j=0..7
// where n' is gate-interleaved: n' = jrow*4 + g  <- W_hh row g*H + jrow.
__global__ __launch_bounds__(256) void build_wswz(const float* __restrict__ W,
                                                  u16* __restrict__ Wz) {
  int id = blockIdx.x * 256 + threadIdx.x;     // chunk id, total 4H*H/8 = 2M
  int lane = id & 63;
  int k32  = (id >> 6) & 63;
  int n16  = id >> 12;                         // 0..511
  int np = n16 * 16 + (lane & 15);
  int k  = k32 * 32 + (lane >> 4) * 8;
  int g = np & 3, jrow = np >> 2;
  const float* src = W + (size_t)(g * H_DIM + jrow) * H_DIM + k;
  float4 f0 = *(const float4*)(src);
  float4 f1 = *(const float4*)(src + 4);
  ushort4 o0, o1;
  o0.x = f2b(f0.x); o0.y = f2b(f0.y); o0.z = f2b(f0.z); o0.w = f2b(f0.w);
  o1.x = f2b(f1.x); o1.y = f2b(f1.y); o1.z = f2b(f1.z); o1.w = f2b(f1.w);
  u16* dst = Wz + (size_t)id * 8;
  *(ushort4*)(dst) = o0;
  *(ushort4*)(dst + 4) = o1;
}

// epi[n'] = {b_ih+b_hh, W_ih[:,0], W_ih[:,1], 0} at interleaved row n'
__global__ __launch_bounds__(256) void build_epi(const float* __restrict__ b_ih,
                                                 const float* __restrict__ b_hh,
                                                 const float* __restrict__ W_ih,
                                                 float* __restrict__ epi) {
  int np = blockIdx.x * 256 + threadIdx.x;    // 0..8191
  int src = (np & 3) * H_DIM + (np >> 2);
  float4 e;
  e.x = b_ih[src] + b_hh[src];
  e.y = W_ih[src * 2];
  e.z = W_ih[src * 2 + 1];
  e.w = 0.f;
  ((float4*)epi)[np] = e;
}

// ---- plain GEMM (h0 path only, runs once) — verified round-1 code ----
#define BM 64
#define BN 128
#define BK 32
__global__ __launch_bounds__(256) void gemm_bt(const u16* __restrict__ A,
                                               const u16* __restrict__ Bm,
                                               float* __restrict__ C,
                                               int M, int N, int K) {
  __shared__ u16 sA[BM * BK];
  __shared__ u16 sB[BN * BK];
  const int t = threadIdx.x;
  const int bm0 = blockIdx.y * BM, bn0 = blockIdx.x * BN;
  const int wave = t >> 6, lane = t & 63;
  const int wm = (wave >> 1) * 32, wn = (wave & 1) * 64;
  const int r16 = lane & 15, quad = lane >> 4;

  f32x4 acc[2][4];
  const f32x4 z = {0.f, 0.f, 0.f, 0.f};
  for (int i = 0; i < 2; ++i)
    for (int j = 0; j < 4; ++j) acc[i][j] = z;

  const int arow = t >> 2, acg = t & 3;

  for (int k0 = 0; k0 < K; k0 += BK) {
    __syncthreads();
    *(uint4*)&sA[arow * BK + acg * 8] =
        *(const uint4*)&A[(size_t)(bm0 + arow) * K + k0 + acg * 8];
    for (int i = 0; i < 2; ++i) {
      int c = t + 256 * i;
      int row = c >> 2, cg = c & 3;
      *(uint4*)&sB[row * BK + cg * 8] =
          *(const uint4*)&Bm[(size_t)(bn0 + row) * K + k0 + cg * 8];
    }
    __syncthreads();
    bf16x8 af[2], bfr[4];
    for (int mt = 0; mt < 2; ++mt)
      af[mt] = *(const bf16x8*)&sA[(wm + mt * 16 + r16) * BK + quad * 8];
    for (int nt = 0; nt < 4; ++nt)
      bfr[nt] = *(const bf16x8*)&sB[(wn + nt * 16 + r16) * BK + quad * 8];
    for (int mt = 0; mt < 2; ++mt)
      for (int nt = 0; nt < 4; ++nt)
        acc[mt][nt] = __builtin_amdgcn_mfma_f32_16x16x32_bf16(af[mt], bfr[nt],
                                                              acc[mt][nt], 0, 0, 0);
  }
  for (int mt = 0; mt < 2; ++mt)
    for (int nt = 0; nt < 4; ++nt) {
      int row = bm0 + wm + mt * 16 + quad * 4;
      int col = bn0 + wn + nt * 16 + r16;
      for (int r = 0; r < 4; ++r)
        C[(size_t)(row + r) * N + col] = acc[mt][nt][r];
    }
}

// h0pre (B x H, f32, row-major) + b_embed -> h in fragment layout, c=0, x=0.
// h chunk id = (m16*64 + k32)*64 + lane, element j:
//   h[bg = m16*16 + (lane&15)][k = k32*32 + (lane>>4)*8 + j]
__global__ __launch_bounds__(256) void init_state(const float* __restrict__ h0pre,
                                                  const float* __restrict__ b_embed,
                                                  u16* __restrict__ h,
                                                  float* __restrict__ c,
                                                  float* __restrict__ x) {
  int idx = blockIdx.x * 256 + threadIdx.x;  // B*H
  int bg = idx >> 11, k = idx & (H_DIM - 1);
  float v = h0pre[idx] + b_embed[k];
  size_t chunk = (((size_t)(bg >> 4)) * 64 + (k >> 5)) * 64 + ((k >> 3) & 3) * 16 + (bg & 15);
  size_t pos = chunk * 8 + (k & 7);
  h[pos] = f2b(v);
  c[pos] = 0.f;
  if (idx < B_DIM * 2) x[idx] = 0.f;
}

// ---- fused step: LDS-free K-loop + LSTM epilogue ----
// hA: h_in fragment layout; Wz: W fragment layout; c/h_out: fragment layout.
// Grid = 256 blocks x 512 threads. Block tile 128(m) x 128(n'); 8 waves of 32x64.
// bid swizzle pins each n-tile group to one XCD (W slice = 4 MB = per-XCD L2).
__global__ __launch_bounds__(512) void gemm_lstm(const u16* __restrict__ hA,
                                                 const u16* __restrict__ Wz,
                                                 const float* __restrict__ epi,
                                                 const float* __restrict__ x,
                                                 float* __restrict__ c,
                                                 u16* __restrict__ h_out) {
  __shared__ float gt[64 * 132];               // 33792 B epilogue tile (half rows)

  const int bid = blockIdx.x;
  const int x8 = bid & 7, nlo = (bid >> 3) & 7, mt = bid >> 6;
  const int nt = x8 * 8 + nlo;                 // 0..63
  const int bm0 = mt * 128;

  const int t = threadIdx.x, wv = t >> 6, ln = t & 63;
  const int wm = (wv & 3) * 32, wn = (wv >> 2) * 64;
  const int r16 = ln & 15, quad = ln >> 4;

  // fragment base pointers (u16 units); chunk = (tile16*64 + k32)*64 + lane
  const u16* pA[2];
  const u16* pB[4];
  for (int i = 0; i < 2; ++i)
    pA[i] = hA + (((size_t)((bm0 >> 4) + (wm >> 4) + i)) * 4096 + ln) * 8;
  for (int i = 0; i < 4; ++i)
    pB[i] = Wz + (((size_t)(nt * 8 + (wn >> 4) + i)) * 4096 + ln) * 8;

  f32x4 acc[2][4];
  const f32x4 z = {0.f, 0.f, 0.f, 0.f};
  for (int i = 0; i < 2; ++i)
    for (int j = 0; j < 4; ++j) acc[i][j] = z;

  bf16x8 a[4][2], b[4][4];
  // preload k32 = 0,1,2 into slots 0,1,2
  for (int p = 0; p < 3; ++p) {
    for (int i = 0; i < 2; ++i) a[p][i] = *(const bf16x8*)(pA[i] + (size_t)p * 512);
    for (int i = 0; i < 4; ++i) b[p][i] = *(const bf16x8*)(pB[i] + (size_t)p * 512);
  }

#pragma unroll 4
  for (int k32 = 0; k32 < 64; ++k32) {
    const int s = k32 & 3;
    const int kp = k32 + 3;
    if (kp < 64) {
      const int sp = kp & 3;
      for (int i = 0; i < 2; ++i) a[sp][i] = *(const bf16x8*)(pA[i] + (size_t)kp * 512);
      for (int i = 0; i < 4; ++i) b[sp][i] = *(const bf16x8*)(pB[i] + (size_t)kp * 512);
    }
    for (int mi = 0; mi < 2; ++mi)
      for (int ni = 0; ni < 4; ++ni)
        acc[mi][ni] = __builtin_amdgcn_mfma_f32_16x16x32_bf16(a[s][mi], b[s][ni],
                                                              acc[mi][ni], 0, 0, 0);
  }

  // epilogue in two 64-row rounds (LDS 64x132 f32)
  for (int half = 0; half < 2; ++half) {
    __syncthreads();
    if (((wv & 3) >> 1) == half) {             // writer waves (wave-uniform)
      const int wmr = (wv & 1) * 32;
      for (int mi = 0; mi < 2; ++mi)
        for (int ni = 0; ni < 4; ++ni) {
          int row = wmr + mi * 16 + quad * 4;
          int col = wn + ni * 16 + r16;
          for (int r = 0; r < 4; ++r)
            gt[(row + r) * 132 + col] = acc[mi][ni][r];
        }
    }
    __syncthreads();
    if ((wv >> 2) == half) {                   // reader waves (wave-uniform)
      const int lrow = (wv & 3) * 16 + r16;    // local row 0..63
      const int bg = bm0 + half * 64 + lrow;   // batch index
      const float x0 = x[bg * 2 + 0], x1 = x[bg * 2 + 1];
      const size_t chunk = (((size_t)(bg >> 4)) * 64 + nt) * 64 + ln;
      float cv[8]; u16 hv[8];
      const float4* epi4 = (const float4*)epi;
      for (int j = 0; j < 8; ++j) {
        int col = quad * 32 + j * 4;
        float4 g4 = *(const float4*)&gt[lrow * 132 + col];
        float4 e0 = epi4[nt * 128 + col + 0];
        float4 e1 = epi4[nt * 128 + col + 1];
        float4 e2 = epi4[nt * 128 + col + 2];
        float4 e3 = epi4[nt * 128 + col + 3];
        float gi = g4.x + e0.x + x0 * e0.y + x1 * e0.z;
        float gf = g4.y + e1.x + x0 * e1.y + x1 * e1.z;
        float gg = g4.z + e2.x + x0 * e2.y + x1 * e2.z;
        float go = g4.w + e3.x + x0 * e3.y + x1 * e3.z;
        float si = 1.f / (1.f + __expf(-gi));
        float sf = 1.f / (1.f + __expf(-gf));
        float so = 1.f / (1.f + __expf(-go));
        float cn = sf * c[chunk * 8 + j] + si * tanhf(gg);
        cv[j] = cn;
        hv[j] = f2b(so * tanhf(cn));
      }
      *(float4*)&c[chunk * 8 + 0] = *(float4*)&cv[0];
      *(float4*)&c[chunk * 8 + 4] = *(float4*)&cv[4];
      *(ushort4*)&h_out[chunk * 8 + 0] = *(ushort4*)&hv[0];
      *(ushort4*)&h_out[chunk * 8 + 4] = *(ushort4*)&hv[4];
    }
  }
}

// out_head over fragment-layout h
__global__ __launch_bounds__(256) void out_head(const u16* __restrict__ h,
                                                const float* __restrict__ W_out,
                                                const float* __restrict__ b_out,
                                                const float* __restrict__ W_stop,
                                                const float* __restrict__ b_stop,
                                                float* __restrict__ coords,
                                                float* __restrict__ stops,
                                                float* __restrict__ x, int t) {
  int bb = blockIdx.x;                          // batch
  int tid = threadIdx.x;
  int k32 = tid >> 2, qd = tid & 3;
  size_t chunk = (((size_t)(bb >> 4)) * 64 + k32) * 64 + qd * 16 + (bb & 15);
  bf16x8 h8 = *(const bf16x8*)&h[chunk * 8];
  int kb = k32 * 32 + qd * 8;
  float s0 = 0.f, s1 = 0.f, s2 = 0.f;
  for (int j = 0; j < 8; ++j) {
    float hv = b2f((u16)h8[j]);
    s0 += hv * W_out[kb + j];
    s1 += hv * W_out[H_DIM + kb + j];
    s2 += hv * W_stop[kb + j];
  }
  for (int off = 32; off > 0; off >>= 1) {
    s0 += __shfl_down(s0, off);
    s1 += __shfl_down(s1, off);
    s2 += __shfl_down(s2, off);
  }
  __shared__ float red[4][3];
  int wave = tid >> 6, lane = tid & 63;
  if (lane == 0) { red[wave][0] = s0; red[wave][1] = s1; red[wave][2] = s2; }
  __syncthreads();
  if (tid == 0) {
    float c0 = red[0][0] + red[1][0] + red[2][0] + red[3][0] + b_out[0];
    float c1 = red[0][1] + red[1][1] + red[2][1] + red[3][1] + b_out[1];
    float sv = red[0][2] + red[1][2] + red[2][2] + red[3][2] + b_stop[0];
    float st = 1.f / (1.f + __expf(-sv));
    coords[((size_t)bb * T_DIM + t) * 2 + 0] = c0;
    coords[((size_t)bb * T_DIM + t) * 2 + 1] = c1;
    stops[(size_t)bb * T_DIM + t] = st;
    x[bb * 2 + 0] = c0;
    x[bb * 2 + 1] = c1;
  }
}

extern "C" void kernel_launch(void* const* d_in, const int* in_sizes, int n_in,
                              void* d_out, int out_size, void* d_ws, size_t ws_size,
                              hipStream_t stream) {
  const float* embedding = (const float*)d_in[0];
  const float* W_embed   = (const float*)d_in[2];
  const float* b_embed   = (const float*)d_in[3];
  const float* W_ih      = (const float*)d_in[4];
  const float* b_ih      = (const float*)d_in[5];
  const float* W_hh      = (const float*)d_in[6];
  const float* b_hh      = (const float*)d_in[7];
  const float* W_out     = (const float*)d_in[8];
  const float* b_out     = (const float*)d_in[9];
  const float* W_stop    = (const float*)d_in[10];
  const float* b_stop    = (const float*)d_in[11];

  float* coords = (float*)d_out;
  float* stops  = (float*)d_out + (size_t)B_DIM * T_DIM * 2;

  char* ws = (char*)d_ws;
  u16* W_z     = (u16*)ws;   ws += (size_t)G4H * H_DIM * 2;    // 32 MB
  u16* W_emb_b = (u16*)ws;   ws += (size_t)H_DIM * E_DIM * 2;  // 8 MB
  u16* emb_b   = (u16*)ws;   ws += (size_t)B_DIM * E_DIM * 2;  // 2 MB
  float* h0pre = (float*)ws; ws += (size_t)B_DIM * H_DIM * 4;  // 4 MB
  float* epi   = (float*)ws; ws += (size_t)G4H * 4 * 4;        // 128 KB
  float* cbuf  = (float*)ws; ws += (size_t)B_DIM * H_DIM * 4;  // 4 MB
  u16* hbuf0   = (u16*)ws;   ws += (size_t)B_DIM * H_DIM * 2;  // 2 MB
  u16* hbuf1   = (u16*)ws;   ws += (size_t)B_DIM * H_DIM * 2;  // 2 MB
  float* xbuf  = (float*)ws; ws += (size_t)B_DIM * 2 * 4;

  convert_bf16<<<(B_DIM * E_DIM / 4 + 255) / 256, 256, 0, stream>>>(embedding, emb_b, B_DIM * E_DIM / 4);
  convert_bf16<<<(H_DIM * E_DIM / 4 + 255) / 256, 256, 0, stream>>>(W_embed, W_emb_b, H_DIM * E_DIM / 4);
  build_wswz<<<(G4H * H_DIM / 8) / 256, 256, 0, stream>>>(W_hh, W_z);
  build_epi<<<G4H / 256, 256, 0, stream>>>(b_ih, b_hh, W_ih, epi);

  gemm_bt<<<dim3(H_DIM / BN, B_DIM / BM), 256, 0, stream>>>(emb_b, W_emb_b, h0pre,
                                                            B_DIM, H_DIM, E_DIM);
  init_state<<<(B_DIM * H_DIM) / 256, 256, 0, stream>>>(h0pre, b_embed, hbuf0, cbuf, xbuf);

  for (int t = 0; t < T_DIM; ++t) {
    u16* h_in  = (t & 1) ? hbuf1 : hbuf0;
    u16* h_out = (t & 1) ? hbuf0 : hbuf1;
    gemm_lstm<<<256, 512, 0, stream>>>(h_in, W_z, epi, xbuf, cbuf, h_out);
    out_head<<<B_DIM, 256, 0, stream>>>(h_out, W_out, b_out, W_stop, b_stop,
                                        coords, stops, xbuf, t);
  }
}

// Round 4
// 8230.888 us; speedup vs baseline: 1.6329x; 1.1747x over previous
//
#include <hip/hip_runtime.h>
#include <stdint.h>

#define E_DIM 2048
#define H_DIM 2048
#define B_DIM 512
#define T_DIM 256
#define G4H   8192  // 4*H

typedef unsigned short u16;
typedef __attribute__((ext_vector_type(8))) short bf16x8;
typedef __attribute__((ext_vector_type(4))) float f32x4;

__device__ inline u16 f2b(float f) {
  union { float f; uint32_t i; } v; v.f = f;
  uint32_t u = v.i;
  return (u16)((u + 0x7FFFu + ((u >> 16) & 1u)) >> 16);  // RNE
}
__device__ inline float b2f(u16 u) {
  union { uint32_t i; float f; } v; v.i = ((uint32_t)u) << 16; return v.f;
}

__global__ __launch_bounds__(256) void convert_bf16(const float* __restrict__ s,
                                                    u16* __restrict__ d, int n4) {
  int i = blockIdx.x * 256 + threadIdx.x;
  if (i < n4) {
    float4 f = ((const float4*)s)[i];
    ushort4 o;
    o.x = f2b(f.x); o.y = f2b(f.y); o.z = f2b(f.z); o.w = f2b(f.w);
    ((ushort4*)d)[i] = o;
  }
}

// Build W in MFMA-B-fragment order. Chunk id = (n16*64 + k32)*64 + lane holds 8 bf16:
//   B[n' = n16*16 + (lane&15)][k = k32*32 + (lane>>4)*8 + j], j=0..7
// n' gate-interleaved: n' = jrow*4 + g  <- W_hh row g*H + jrow.
__global__ __launch_bounds__(256) void build_wswz(const float* __restrict__ W,
                                                  u16* __restrict__ Wz) {
  int id = blockIdx.x * 256 + threadIdx.x;     // chunk id, total 4H*H/8 = 2M
  int lane = id & 63;
  int k32  = (id >> 6) & 63;
  int n16  = id >> 12;                         // 0..511
  int np = n16 * 16 + (lane & 15);
  int k  = k32 * 32 + (lane >> 4) * 8;
  int g = np & 3, jrow = np >> 2;
  const float* src = W + (size_t)(g * H_DIM + jrow) * H_DIM + k;
  float4 f0 = *(const float4*)(src);
  float4 f1 = *(const float4*)(src + 4);
  ushort4 o0, o1;
  o0.x = f2b(f0.x); o0.y = f2b(f0.y); o0.z = f2b(f0.z); o0.w = f2b(f0.w);
  o1.x = f2b(f1.x); o1.y = f2b(f1.y); o1.z = f2b(f1.z); o1.w = f2b(f1.w);
  u16* dst = Wz + (size_t)id * 8;
  *(ushort4*)(dst) = o0;
  *(ushort4*)(dst + 4) = o1;
}

// epi[n'] = {b_ih+b_hh, W_ih[:,0], W_ih[:,1], 0} at interleaved row n'
__global__ __launch_bounds__(256) void build_epi(const float* __restrict__ b_ih,
                                                 const float* __restrict__ b_hh,
                                                 const float* __restrict__ W_ih,
                                                 float* __restrict__ epi) {
  int np = blockIdx.x * 256 + threadIdx.x;    // 0..8191
  int src = (np & 3) * H_DIM + (np >> 2);
  float4 e;
  e.x = b_ih[src] + b_hh[src];
  e.y = W_ih[src * 2];
  e.z = W_ih[src * 2 + 1];
  e.w = 0.f;
  ((float4*)epi)[np] = e;
}

// ---- plain GEMM (h0 path only, runs once) ----
#define BM 64
#define BN 128
#define BK 32
__global__ __launch_bounds__(256) void gemm_bt(const u16* __restrict__ A,
                                               const u16* __restrict__ Bm,
                                               float* __restrict__ C,
                                               int M, int N, int K) {
  __shared__ u16 sA[BM * BK];
  __shared__ u16 sB[BN * BK];
  const int t = threadIdx.x;
  const int bm0 = blockIdx.y * BM, bn0 = blockIdx.x * BN;
  const int wave = t >> 6, lane = t & 63;
  const int wm = (wave >> 1) * 32, wn = (wave & 1) * 64;
  const int r16 = lane & 15, quad = lane >> 4;

  f32x4 acc[2][4];
  const f32x4 z = {0.f, 0.f, 0.f, 0.f};
  for (int i = 0; i < 2; ++i)
    for (int j = 0; j < 4; ++j) acc[i][j] = z;

  const int arow = t >> 2, acg = t & 3;

  for (int k0 = 0; k0 < K; k0 += BK) {
    __syncthreads();
    *(uint4*)&sA[arow * BK + acg * 8] =
        *(const uint4*)&A[(size_t)(bm0 + arow) * K + k0 + acg * 8];
    for (int i = 0; i < 2; ++i) {
      int c = t + 256 * i;
      int row = c >> 2, cg = c & 3;
      *(uint4*)&sB[row * BK + cg * 8] =
          *(const uint4*)&Bm[(size_t)(bn0 + row) * K + k0 + cg * 8];
    }
    __syncthreads();
    bf16x8 af[2], bfr[4];
    for (int mt = 0; mt < 2; ++mt)
      af[mt] = *(const bf16x8*)&sA[(wm + mt * 16 + r16) * BK + quad * 8];
    for (int nt = 0; nt < 4; ++nt)
      bfr[nt] = *(const bf16x8*)&sB[(wn + nt * 16 + r16) * BK + quad * 8];
    for (int mt = 0; mt < 2; ++mt)
      for (int nt = 0; nt < 4; ++nt)
        acc[mt][nt] = __builtin_amdgcn_mfma_f32_16x16x32_bf16(af[mt], bfr[nt],
                                                              acc[mt][nt], 0, 0, 0);
  }
  for (int mt = 0; mt < 2; ++mt)
    for (int nt = 0; nt < 4; ++nt) {
      int row = bm0 + wm + mt * 16 + quad * 4;
      int col = bn0 + wn + nt * 16 + r16;
      for (int r = 0; r < 4; ++r)
        C[(size_t)(row + r) * N + col] = acc[mt][nt][r];
    }
}

// h0pre (B x H, f32) + b_embed -> h fragment layout, c=0, x=0.
__global__ __launch_bounds__(256) void init_state(const float* __restrict__ h0pre,
                                                  const float* __restrict__ b_embed,
                                                  u16* __restrict__ h,
                                                  float* __restrict__ c,
                                                  float* __restrict__ x) {
  int idx = blockIdx.x * 256 + threadIdx.x;  // B*H
  int bg = idx >> 11, k = idx & (H_DIM - 1);
  float v = h0pre[idx] + b_embed[k];
  size_t chunk = (((size_t)(bg >> 4)) * 64 + (k >> 5)) * 64 + ((k >> 3) & 3) * 16 + (bg & 15);
  size_t pos = chunk * 8 + (k & 7);
  h[pos] = f2b(v);
  c[pos] = 0.f;
  if (idx < B_DIM * 2) x[idx] = 0.f;
}

// ---- fused step: LDS-free K-loop, 64x64 wave tiles, K split across wave pairs ----
// 8 waves: q = wv&3 spatial quadrant (qm = q&1 m-half, qn = q>>1 n-half),
// kh = wv>>2 K-half. Partial accs combined via LDS, then LSTM epilogue.
__global__ __launch_bounds__(512) void gemm_lstm(const u16* __restrict__ hA,
                                                 const u16* __restrict__ Wz,
                                                 const float* __restrict__ epi,
                                                 const float* __restrict__ x,
                                                 float* __restrict__ c,
                                                 u16* __restrict__ h_out) {
  __shared__ char smem[33792];
  float* gt   = (float*)smem;    // 64 x 132 f32 epilogue tile
  float* comb = (float*)smem;    // 2 x 4096 f32 combine buffers

  const int bid = blockIdx.x;
  const int nt = (bid & 7) * 8 + ((bid >> 3) & 7);   // XCD-pinned n-tile
  const int mt = bid >> 6;
  const int bm0 = mt * 128;

  const int t = threadIdx.x, wv = t >> 6, ln = t & 63;
  const int q = wv & 3, kh = wv >> 2;
  const int qm = q & 1, qn = q >> 1;
  const int r16 = ln & 15, quad = ln >> 4;

  // fragment base pointers (u16 units); element offset = m16*32768 + k32*512 + ln*8
  const u16* pA[4];
  const u16* pB[4];
  for (int i = 0; i < 4; ++i) {
    pA[i] = hA + (size_t)((bm0 >> 4) + qm * 4 + i) * 32768 +
            (size_t)(kh * 32) * 512 + ln * 8;
    pB[i] = Wz + (size_t)(nt * 8 + qn * 4 + i) * 32768 +
            (size_t)(kh * 32) * 512 + ln * 8;
  }

  f32x4 acc[4][4];
  const f32x4 z = {0.f, 0.f, 0.f, 0.f};
  for (int i = 0; i < 4; ++i)
    for (int j = 0; j < 4; ++j) acc[i][j] = z;

  bf16x8 af[2][4], bf[2][4];
  for (int i = 0; i < 4; ++i) {
    af[0][i] = *(const bf16x8*)(pA[i]);
    bf[0][i] = *(const bf16x8*)(pB[i]);
  }

#pragma unroll 2
  for (int kk = 0; kk < 32; ++kk) {
    const int s = kk & 1;
    if (kk + 1 < 32) {
      const int sp = s ^ 1;
      for (int i = 0; i < 4; ++i) {
        af[sp][i] = *(const bf16x8*)(pA[i] + (size_t)(kk + 1) * 512);
        bf[sp][i] = *(const bf16x8*)(pB[i] + (size_t)(kk + 1) * 512);
      }
    }
    for (int mi = 0; mi < 4; ++mi)
      for (int ni = 0; ni < 4; ++ni)
        acc[mi][ni] = __builtin_amdgcn_mfma_f32_16x16x32_bf16(af[s][mi], bf[s][ni],
                                                              acc[mi][ni], 0, 0, 0);
  }

  // combine K-halves: kh=1 exports via LDS, kh=0 adds (2 rounds by qn)
  for (int r = 0; r < 2; ++r) {
    __syncthreads();
    if (kh == 1 && qn == r) {
      float* dst = comb + qm * 4096;
      for (int mi = 0; mi < 4; ++mi)
        for (int ni = 0; ni < 4; ++ni)
          *(f32x4*)&dst[((mi * 4 + ni) * 64 + ln) * 4] = acc[mi][ni];
    }
    __syncthreads();
    if (kh == 0 && qn == r) {
      const float* src = comb + qm * 4096;
      for (int mi = 0; mi < 4; ++mi)
        for (int ni = 0; ni < 4; ++ni) {
          f32x4 p = *(const f32x4*)&src[((mi * 4 + ni) * 64 + ln) * 4];
          acc[mi][ni] += p;
        }
    }
  }

  // epilogue in two 64-row halves
  for (int half = 0; half < 2; ++half) {
    __syncthreads();
    if (kh == 0 && qm == half) {               // 2 writer waves (qn = 0,1)
      for (int mi = 0; mi < 4; ++mi)
        for (int ni = 0; ni < 4; ++ni) {
          int row = mi * 16 + quad * 4;        // local 0..63
          int col = qn * 64 + ni * 16 + r16;   // 0..127
          for (int r = 0; r < 4; ++r)
            gt[(row + r) * 132 + col] = acc[mi][ni][r];
        }
    }
    __syncthreads();
    if (kh == half) {                          // 4 reader waves
      const int lrow = q * 16 + r16;           // 0..63
      const int bg = bm0 + half * 64 + lrow;
      const float x0 = x[bg * 2 + 0], x1 = x[bg * 2 + 1];
      const size_t chunk = (((size_t)(bg >> 4)) * 64 + nt) * 64 + ln;
      float cv[8]; u16 hv[8];
      const float4* epi4 = (const float4*)epi;
      for (int j = 0; j < 8; ++j) {
        int col = quad * 32 + j * 4;
        float4 g4 = *(const float4*)&gt[lrow * 132 + col];
        float4 e0 = epi4[nt * 128 + col + 0];
        float4 e1 = epi4[nt * 128 + col + 1];
        float4 e2 = epi4[nt * 128 + col + 2];
        float4 e3 = epi4[nt * 128 + col + 3];
        float gi = g4.x + e0.x + x0 * e0.y + x1 * e0.z;
        float gf = g4.y + e1.x + x0 * e1.y + x1 * e1.z;
        float gg = g4.z + e2.x + x0 * e2.y + x1 * e2.z;
        float go = g4.w + e3.x + x0 * e3.y + x1 * e3.z;
        float si = 1.f / (1.f + __expf(-gi));
        float sf = 1.f / (1.f + __expf(-gf));
        float so = 1.f / (1.f + __expf(-go));
        float cn = sf * c[chunk * 8 + j] + si * tanhf(gg);
        cv[j] = cn;
        hv[j] = f2b(so * tanhf(cn));
      }
      *(float4*)&c[chunk * 8 + 0] = *(float4*)&cv[0];
      *(float4*)&c[chunk * 8 + 4] = *(float4*)&cv[4];
      *(ushort4*)&h_out[chunk * 8 + 0] = *(ushort4*)&hv[0];
      *(ushort4*)&h_out[chunk * 8 + 4] = *(ushort4*)&hv[4];
    }
  }
}

// out_head over fragment-layout h
__global__ __launch_bounds__(256) void out_head(const u16* __restrict__ h,
                                                const float* __restrict__ W_out,
                                                const float* __restrict__ b_out,
                                                const float* __restrict__ W_stop,
                                                const float* __restrict__ b_stop,
                                                float* __restrict__ coords,
                                                float* __restrict__ stops,
                                                float* __restrict__ x, int t) {
  int bb = blockIdx.x;
  int tid = threadIdx.x;
  int k32 = tid >> 2, qd = tid & 3;
  size_t chunk = (((size_t)(bb >> 4)) * 64 + k32) * 64 + qd * 16 + (bb & 15);
  bf16x8 h8 = *(const bf16x8*)&h[chunk * 8];
  int kb = k32 * 32 + qd * 8;
  float s0 = 0.f, s1 = 0.f, s2 = 0.f;
  for (int j = 0; j < 8; ++j) {
    float hv = b2f((u16)h8[j]);
    s0 += hv * W_out[kb + j];
    s1 += hv * W_out[H_DIM + kb + j];
    s2 += hv * W_stop[kb + j];
  }
  for (int off = 32; off > 0; off >>= 1) {
    s0 += __shfl_down(s0, off);
    s1 += __shfl_down(s1, off);
    s2 += __shfl_down(s2, off);
  }
  __shared__ float red[4][3];
  int wave = tid >> 6, lane = tid & 63;
  if (lane == 0) { red[wave][0] = s0; red[wave][1] = s1; red[wave][2] = s2; }
  __syncthreads();
  if (tid == 0) {
    float c0 = red[0][0] + red[1][0] + red[2][0] + red[3][0] + b_out[0];
    float c1 = red[0][1] + red[1][1] + red[2][1] + red[3][1] + b_out[1];
    float sv = red[0][2] + red[1][2] + red[2][2] + red[3][2] + b_stop[0];
    float st = 1.f / (1.f + __expf(-sv));
    coords[((size_t)bb * T_DIM + t) * 2 + 0] = c0;
    coords[((size_t)bb * T_DIM + t) * 2 + 1] = c1;
    stops[(size_t)bb * T_DIM + t] = st;
    x[bb * 2 + 0] = c0;
    x[bb * 2 + 1] = c1;
  }
}

extern "C" void kernel_launch(void* const* d_in, const int* in_sizes, int n_in,
                              void* d_out, int out_size, void* d_ws, size_t ws_size,
                              hipStream_t stream) {
  const float* embedding = (const float*)d_in[0];
  const float* W_embed   = (const float*)d_in[2];
  const float* b_embed   = (const float*)d_in[3];
  const float* W_ih      = (const float*)d_in[4];
  const float* b_ih      = (const float*)d_in[5];
  const float* W_hh      = (const float*)d_in[6];
  const float* b_hh      = (const float*)d_in[7];
  const float* W_out     = (const float*)d_in[8];
  const float* b_out     = (const float*)d_in[9];
  const float* W_stop    = (const float*)d_in[10];
  const float* b_stop    = (const float*)d_in[11];

  float* coords = (float*)d_out;
  float* stops  = (float*)d_out + (size_t)B_DIM * T_DIM * 2;

  char* ws = (char*)d_ws;
  u16* W_z     = (u16*)ws;   ws += (size_t)G4H * H_DIM * 2;    // 32 MB
  u16* W_emb_b = (u16*)ws;   ws += (size_t)H_DIM * E_DIM * 2;  // 8 MB
  u16* emb_b   = (u16*)ws;   ws += (size_t)B_DIM * E_DIM * 2;  // 2 MB
  float* h0pre = (float*)ws; ws += (size_t)B_DIM * H_DIM * 4;  // 4 MB
  float* epi   = (float*)ws; ws += (size_t)G4H * 4 * 4;        // 128 KB
  float* cbuf  = (float*)ws; ws += (size_t)B_DIM * H_DIM * 4;  // 4 MB
  u16* hbuf0   = (u16*)ws;   ws += (size_t)B_DIM * H_DIM * 2;  // 2 MB
  u16* hbuf1   = (u16*)ws;   ws += (size_t)B_DIM * H_DIM * 2;  // 2 MB
  float* xbuf  = (float*)ws; ws += (size_t)B_DIM * 2 * 4;

  convert_bf16<<<(B_DIM * E_DIM / 4 + 255) / 256, 256, 0, stream>>>(embedding, emb_b, B_DIM * E_DIM / 4);
  convert_bf16<<<(H_DIM * E_DIM / 4 + 255) / 256, 256, 0, stream>>>(W_embed, W_emb_b, H_DIM * E_DIM / 4);
  build_wswz<<<(G4H * H_DIM / 8) / 256, 256, 0, stream>>>(W_hh, W_z);
  build_epi<<<G4H / 256, 256, 0, stream>>>(b_ih, b_hh, W_ih, epi);

  gemm_bt<<<dim3(H_DIM / BN, B_DIM / BM), 256, 0, stream>>>(emb_b, W_emb_b, h0pre,
                                                            B_DIM, H_DIM, E_DIM);
  init_state<<<(B_DIM * H_DIM) / 256, 256, 0, stream>>>(h0pre, b_embed, hbuf0, cbuf, xbuf);

  for (int t = 0; t < T_DIM; ++t) {
    u16* h_in  = (t & 1) ? hbuf1 : hbuf0;
    u16* h_out = (t & 1) ? hbuf0 : hbuf1;
    gemm_lstm<<<256, 512, 0, stream>>>(h_in, W_z, epi, xbuf, cbuf, h_out);
    out_head<<<B_DIM, 256, 0, stream>>>(h_out, W_out, b_out, W_stop, b_stop,
                                        coords, stops, xbuf, t);
  }
}